// Round 5
// baseline (146.708 us; speedup 1.0000x reference)
//
#include <hip/hip_runtime.h>
#include <math.h>
#include <stdint.h>

#define NV 50000      // visible nodes
#define NH 5000       // hidden nodes
#define NN 55000      // total nodes
#define NCB 1250      // fine buckets: k>>2, 4 k's each (1250*4 = 5000 exactly)
#define NCBP 1280     // padded bucket-array width (LDS)
#define CSTRIDE 16    // coarse_cnt stride: 1 counter per 64B line (atomic contention fix)
#define BCAP 1280     // region capacity per fine bucket (mean 800, +17 sigma)
#define KSLOT 384     // per-k cap (mean 200, +13 sigma; validated)
#define CHUNK 4096    // split-pass edges per block

// ws layout:
//   bits       : 0      , NV*4 u32        = 800000 B (128-bit spin mask per visible)
//   coarse_cnt : 800000 , NCB*16 u32      = 80000 B (one counter per 64B line)
//   recs       : 880000 , NCB*BCAP*8      = 12.8 MB (uint2 {v | (k&3)<<16, w_bits})

// sign-select mask: 0xFFFFFFFF if bit bsh of word set, else 0 (v_bfe_i32)
__device__ __forceinline__ uint32_t selmask(uint32_t word, uint32_t bsh) {
#if __has_builtin(__builtin_amdgcn_sbfe)
    return (uint32_t)__builtin_amdgcn_sbfe((int)word, bsh, 1u);
#else
    return (uint32_t)((int32_t)(word << (31u - bsh)) >> 31);
#endif
}

// Pass 0: bit-pack s; block 0 zeros coarse_cnt (replaces hipMemsetAsync).
__global__ void __launch_bounds__(256) pack_zero_kernel(
        const int* __restrict__ s, uint32_t* __restrict__ bits,
        uint32_t* __restrict__ coarse_cnt) {
    if (blockIdx.x == 0)
        for (int i = threadIdx.x; i < NCB * CSTRIDE; i += 256) coarse_cnt[i] = 0u;
    int tid = blockIdx.x * 256 + threadIdx.x;
    int v = tid >> 2;
    int g = tid & 3;
    if (v >= NV) return;
    const int* col = s + (size_t)g * 32 * NN + v;
    uint32_t w = 0;
#pragma unroll
    for (int j = 0; j < 32; ++j)
        w |= (uint32_t)(col[(size_t)j * NN] & 1) << j;
    bits[(size_t)v * 4 + g] = w;   // consecutive tid -> consecutive addresses
}

// Pass A: chunked split. Phase 1's LDS atomicAdd return IS the within-chunk
// rank (regs) -> no second LDS-atomic pass. Reserve phase: one returning
// global atomic per nonempty bucket — counters PADDED to one per 64B line.
// Theory: R2 calibrated contended-atomic service at ~46cyc/same-line-hit;
// the old dense coarse_cnt (79 lines, ~3700 hits/line) made this phase
// ~18us — split's real cost, invariant across R0-R4's neutral results.
__global__ void __launch_bounds__(256) split_kernel(
        const int4* __restrict__ seg4, const int4* __restrict__ adj4,
        const float4* __restrict__ quad4,
        uint32_t* __restrict__ coarse_cnt, uint2* __restrict__ recs, int E) {
    __shared__ uint32_t hist[NCBP];    // per-bucket count this chunk (final after ph1)
    __shared__ uint32_t gbase[NCBP];   // reserved global run base
    const int tid = threadIdx.x;
    for (int i = tid; i < NCBP; i += 256) hist[i] = 0u;
    __syncthreads();

    const int c0 = blockIdx.x * CHUNK;
    const int nloc = min(CHUNK, E - c0);          // E, c0 multiples of 4
    const int t4max = (c0 + nloc) >> 2;
    int kreg[16];
    int rnk[16];
#pragma unroll
    for (int j = 0; j < 4; ++j) {
        int t4 = (c0 >> 2) + j * 256 + tid;
        bool ok = t4 < t4max;
        int4 sg = ok ? seg4[t4] : make_int4(-1, -1, -1, -1);
        kreg[j * 4 + 0] = sg.x; kreg[j * 4 + 1] = sg.y;
        kreg[j * 4 + 2] = sg.z; kreg[j * 4 + 3] = sg.w;
        if (ok) {
            rnk[j * 4 + 0] = (int)atomicAdd(&hist[sg.x >> 2], 1u);
            rnk[j * 4 + 1] = (int)atomicAdd(&hist[sg.y >> 2], 1u);
            rnk[j * 4 + 2] = (int)atomicAdd(&hist[sg.z >> 2], 1u);
            rnk[j * 4 + 3] = (int)atomicAdd(&hist[sg.w >> 2], 1u);
        }
    }
    __syncthreads();
    for (int i = tid; i < NCB; i += 256) {
        uint32_t h = hist[i];
        if (h) gbase[i] = atomicAdd(&coarse_cnt[i * CSTRIDE], h);
    }
    __syncthreads();
#pragma unroll
    for (int j = 0; j < 4; ++j) {
        int t4 = (c0 >> 2) + j * 256 + tid;
        if (t4 < t4max) {
            int4 a = adj4[t4];
            float4 q = quad4[t4];   // flat_j_idx == arange(E)
#pragma unroll
            for (int cmp = 0; cmp < 4; ++cmp) {
                int k = kreg[j * 4 + cmp];
                int v = (cmp == 0) ? a.x : (cmp == 1) ? a.y : (cmp == 2) ? a.z : a.w;
                float w = (cmp == 0) ? q.x : (cmp == 1) ? q.y : (cmp == 2) ? q.z : q.w;
                int bk = k >> 2;
                uint32_t pos = gbase[bk] + (uint32_t)rnk[j * 4 + cmp];
                if (pos < BCAP)
                    recs[(size_t)bk * BCAP + pos] =
                        make_uint2((uint32_t)v | ((uint32_t)(k & 3) << 16),
                                   __float_as_uint(w));
            }
        }
    }
}

// Pass B: R1-proven form, verbatim (8 blocks/CU is load-bearing — R4 lesson).
// One block per 4 k's, 2 rounds x 2 k's; region scan scatters into per-k
// rows; accumulate acc = sum(w & selmask); eff = 2*acc - sum_w + linear.
__global__ void __launch_bounds__(256, 8) field_kernel(
        const uint32_t* __restrict__ coarse_cnt, const uint2* __restrict__ recs,
        const uint4* __restrict__ bits4, const float* __restrict__ linear,
        float* __restrict__ out) {
    const int x = blockIdx.x;
    const int blk = (x & 7) * 157 + (x >> 3);   // XCD-contiguous block index
    if (blk >= NCB) return;                      // 6 idle blocks
    const int tid = threadIdx.x;

    __shared__ uint32_t cur2[2];
    __shared__ float swp[4][2];                            // per-wave sum_w partials
    __shared__ __align__(16) uint32_t rows[2][5][KSLOT];   // 15.4 KB
    __shared__ float part[2][256];                         // 2 KB

    const int cnt = (int)min(coarse_cnt[blk * CSTRIDE], (uint32_t)BCAP);
    const uint2* __restrict__ region = recs + (size_t)blk * BCAP;

    const int b = tid & 127;
    const int grp = tid >> 7;          // 0/1: record-half
    const uint32_t bsh = (uint32_t)(b & 31);
    const int widx = b >> 5;
    const int lane = tid & 63;
    const int wid = tid >> 6;

    for (int rnd = 0; rnd < 2; ++rnd) {
        if (tid < 2) cur2[tid] = 0u;
        __syncthreads();

        // scan + stage: keep records with kl>>1 == rnd
        float s0 = 0.f, s1 = 0.f;
        for (int i = tid; i < cnt; i += 256) {
            uint2 r = region[i];
            int kl = (int)((r.x >> 16) & 3u);
            if ((kl >> 1) == rnd) {
                int kk = kl & 1;
                uint32_t p = atomicAdd(&cur2[kk], 1u);
                if (p < KSLOT) {
                    uint4 mw = bits4[r.x & 0xFFFFu];   // L2/L3-resident gather
                    rows[kk][0][p] = mw.x;
                    rows[kk][1][p] = mw.y;
                    rows[kk][2][p] = mw.z;
                    rows[kk][3][p] = mw.w;
                    rows[kk][4][p] = r.y;
                    float w = __uint_as_float(r.y);
                    if (kk == 0) s0 += w; else s1 += w;
                }
            }
        }
#pragma unroll
        for (int off = 32; off; off >>= 1) {
            s0 += __shfl_down(s0, off);
            s1 += __shfl_down(s1, off);
        }
        if (lane == 0) { swp[wid][0] = s0; swp[wid][1] = s1; }
        __syncthreads();

        // pad w rows to multiple of 8 (stale mask rows killed by w=0)
        const int c0v = min((int)cur2[0], KSLOT);
        const int c1v = min((int)cur2[1], KSLOT);
        const int T0 = (c0v + 7) & ~7;
        const int T1 = (c1v + 7) & ~7;
        for (int t = c0v + tid; t < T0; t += 256) rows[0][4][t] = 0u;
        for (int t = c1v + tid; t < T1; t += 256) rows[1][4][t] = 0u;
        __syncthreads();

        // accumulate: 256 threads = 128 batches x 2 record-halves, per k
#pragma unroll
        for (int kk = 0; kk < 2; ++kk) {
            const int T8k = kk ? T1 : T0;
            const uint32_t* __restrict__ mrow = rows[kk][widx];
            const uint32_t* __restrict__ wrow = rows[kk][4];
            float a0 = 0.f, a1 = 0.f, a2 = 0.f, a3 = 0.f;
            for (int i = grp * 4; i < T8k; i += 8) {
                uint4 mm = *(const uint4*)(mrow + i);   // broadcast ds_read_b128
                uint4 ww = *(const uint4*)(wrow + i);
                a0 += __uint_as_float(ww.x & selmask(mm.x, bsh));
                a1 += __uint_as_float(ww.y & selmask(mm.y, bsh));
                a2 += __uint_as_float(ww.z & selmask(mm.z, bsh));
                a3 += __uint_as_float(ww.w & selmask(mm.w, bsh));
            }
            part[kk][tid] = (a0 + a1) + (a2 + a3);
        }
        __syncthreads();

        if (tid < 128) {
            int k0 = blk * 4 + rnd * 2;                 // k0 even, < 5000 always
            float acc0 = part[0][tid] + part[0][tid + 128];
            float acc1 = part[1][tid] + part[1][tid + 128];
            float e0 = 2.f * acc0 - (swp[0][0] + swp[1][0] + swp[2][0] + swp[3][0])
                       + linear[NV + k0];
            float e1 = 2.f * acc1 - (swp[0][1] + swp[1][1] + swp[2][1] + swp[3][1])
                       + linear[NV + k0 + 1];
            float2 o = make_float2(tanhf(-e0), tanhf(-e1));
            *(float2*)(out + (size_t)tid * NH + k0) = o;  // k0 even -> aligned
        }
        __syncthreads();   // rows/part/swp/cur2 reuse guard
    }
}

extern "C" void kernel_launch(void* const* d_in, const int* in_sizes, int n_in,
                              void* d_out, int out_size, void* d_ws, size_t ws_size,
                              hipStream_t stream) {
    const float* linear = (const float*)d_in[0];
    const float* quad   = (const float*)d_in[1];
    const int*   s      = (const int*)d_in[2];
    const int*   adj    = (const int*)d_in[3];
    const int*   seg    = (const int*)d_in[5];
    const int E = in_sizes[5];
    float* out = (float*)d_out;

    char* ws = (char*)d_ws;
    uint32_t* bits       = (uint32_t*)(ws);
    uint32_t* coarse_cnt = (uint32_t*)(ws + 800000);
    uint2*    recs       = (uint2*)   (ws + 880000);

    pack_zero_kernel<<<(NV * 4 + 255) / 256, 256, 0, stream>>>(s, bits, coarse_cnt);
    const int nchunk = (E + CHUNK - 1) / CHUNK;       // 245
    split_kernel<<<nchunk, 256, 0, stream>>>(
        (const int4*)seg, (const int4*)adj, (const float4*)quad, coarse_cnt, recs, E);
    field_kernel<<<1256, 256, 0, stream>>>(coarse_cnt, recs, (const uint4*)bits,
                                           linear, out);
}

// Round 6
// 134.621 us; speedup vs baseline: 1.0898x; 1.0898x over previous
//
#include <hip/hip_runtime.h>
#include <math.h>
#include <stdint.h>

#define NV 50000      // visible nodes
#define NH 5000       // hidden nodes
#define NN 55000      // total nodes
#define NCB 313       // coarse buckets: k>>4, 16 k's each (313*16 = 5008 >= 5000)
#define BCAP 4096     // region capacity per bucket (mean ~3195, +16 sigma)
#define KSLOT 384     // per-k staging cap (mean 200, +13 sigma)
#define CHUNK 4096    // coarse-pass edges per block

// ws layout:
//   bits       : 0       , NV*4 u32   = 800000 B (128-bit spin mask per visible)
//   coarse_cnt : 800000  , NCB u32    = 1252 B
//   recs       : 801280  , NCB*BCAP*8 = 10.26 MB (uint2 {v | (k&15)<<16, w_bits})

// sign-select mask: 0xFFFFFFFF if bit bsh of word set, else 0 (v_bfe_i32)
__device__ __forceinline__ uint32_t selmask(uint32_t word, uint32_t bsh) {
#if __has_builtin(__builtin_amdgcn_sbfe)
    return (uint32_t)__builtin_amdgcn_sbfe((int)word, bsh, 1u);
#else
    return (uint32_t)((int32_t)(word << (31u - bsh)) >> 31);
#endif
}

// Pass 0: bit-pack s; block 0 zeros coarse_cnt (replaces hipMemsetAsync).
__global__ void __launch_bounds__(256) pack_zero_kernel(
        const int* __restrict__ s, uint32_t* __restrict__ bits,
        uint32_t* __restrict__ coarse_cnt) {
    if (blockIdx.x == 0)
        for (int i = threadIdx.x; i < NCB; i += 256) coarse_cnt[i] = 0u;
    int tid = blockIdx.x * 256 + threadIdx.x;
    int v = tid >> 2;
    int g = tid & 3;
    if (v >= NV) return;
    const int* col = s + (size_t)g * 32 * NN + v;
    uint32_t w = 0;
#pragma unroll
    for (int j = 0; j < 32; ++j)
        w |= (uint32_t)(col[(size_t)j * NN] & 1) << j;
    bits[(size_t)v * 4 + g] = w;   // consecutive tid -> consecutive addresses
}

// Pass A: coarse split (proven). Counting-sort each 4096-edge chunk by
// bucket (k>>4) in LDS, reserve contiguous global runs, drain staged
// records LINEARLY -> coalesced HBM writes.
__global__ void __launch_bounds__(256) coarse_split_kernel(
        const int4* __restrict__ seg4, const int4* __restrict__ adj4,
        const float4* __restrict__ quad4,
        uint32_t* __restrict__ coarse_cnt, uint2* __restrict__ recs, int E) {
    __shared__ uint32_t hist[320];       // per-bucket counts (padded to scan width)
    __shared__ uint32_t loc[320];        // inclusive prefix
    __shared__ uint32_t cur[NCB];        // staging cursor
    __shared__ uint32_t gbase[NCB];      // reserved global run base
    __shared__ __align__(16) uint2 st[CHUNK];   // 32 KB staging
    __shared__ uint32_t dst[CHUNK];             // absolute dest, ~0u = dropped
    const int tid = threadIdx.x;
    for (int i = tid; i < 320; i += 256) hist[i] = 0u;
    __syncthreads();

    const int c0 = blockIdx.x * CHUNK;
    const int nloc = min(CHUNK, E - c0);         // E, c0 multiples of 4
    int kreg[16];
#pragma unroll
    for (int j = 0; j < 4; ++j) {
        int t4 = (c0 >> 2) + j * 256 + tid;
        bool ok = t4 < ((c0 + nloc) >> 2);
        int4 sg = ok ? seg4[t4] : make_int4(-1, -1, -1, -1);
        kreg[j * 4 + 0] = sg.x; kreg[j * 4 + 1] = sg.y;
        kreg[j * 4 + 2] = sg.z; kreg[j * 4 + 3] = sg.w;
        if (ok) {
            atomicAdd(&hist[sg.x >> 4], 1u);
            atomicAdd(&hist[sg.y >> 4], 1u);
            atomicAdd(&hist[sg.z >> 4], 1u);
            atomicAdd(&hist[sg.w >> 4], 1u);
        }
    }
    __syncthreads();
    for (int i = tid; i < NCB; i += 256)
        gbase[i] = atomicAdd(&coarse_cnt[i], hist[i]);
    for (int i = tid; i < 320; i += 256) loc[i] = hist[i];
    __syncthreads();
    for (int d = 1; d < 320; d <<= 1) {          // Hillis-Steele scan
        uint32_t v0 = 0, v1 = 0;
        int i1 = tid + 256;
        if (tid >= d) v0 = loc[tid - d];
        if (i1 < 320 && i1 >= d) v1 = loc[i1 - d];
        __syncthreads();
        if (tid >= d) loc[tid] += v0;
        if (i1 < 320 && i1 >= d) loc[i1] += v1;
        __syncthreads();
    }
    for (int i = tid; i < NCB; i += 256) cur[i] = loc[i] - hist[i];  // exclusive
    __syncthreads();
#pragma unroll
    for (int j = 0; j < 4; ++j) {
        int t4 = (c0 >> 2) + j * 256 + tid;
        if (t4 < ((c0 + nloc) >> 2)) {
            int4 a = adj4[t4];
            float4 q = quad4[t4];   // flat_j_idx == arange(E)
#pragma unroll
            for (int cmp = 0; cmp < 4; ++cmp) {
                int k = kreg[j * 4 + cmp];
                int v = (cmp == 0) ? a.x : (cmp == 1) ? a.y : (cmp == 2) ? a.z : a.w;
                float w = (cmp == 0) ? q.x : (cmp == 1) ? q.y : (cmp == 2) ? q.z : q.w;
                int bk = k >> 4;
                uint32_t slot = atomicAdd(&cur[bk], 1u);
                uint32_t rank = gbase[bk] + (slot - (loc[bk] - hist[bk]));
                st[slot] = make_uint2((uint32_t)v | ((uint32_t)(k & 15) << 16),
                                      __float_as_uint(w));
                dst[slot] = (rank < BCAP) ? (uint32_t)bk * BCAP + rank : ~0u;
            }
        }
    }
    __syncthreads();
    for (int i = tid; i < nloc; i += 256) {
        uint32_t d = dst[i];
        if (d != ~0u) recs[d] = st[i];
    }
}

// Pass B: quarter-bucket field. Block = 4 k's (quarter of a bucket), 256
// threads, ~30 KB LDS -> ~5 blocks/CU. Single region scan scatters matching
// records into 4 fixed per-k LDS segments. Then 2 rounds x 2 k's: stage
// bit-words + w rows (one uint4 bits-gather/record), accumulate
// acc = sum(w & selmask), eff = 2*acc - sum_w + linear. Swizzle puts a
// bucket's 4 quarters on one XCD (full 64B out-line assembly).
__global__ void __launch_bounds__(256) quarter_field_kernel(
        const uint32_t* __restrict__ coarse_cnt, const uint2* __restrict__ recs,
        const uint4* __restrict__ bits4, const float* __restrict__ linear,
        float* __restrict__ out) {
    const int x = blockIdx.x;
    const int j = (x & 7) * 157 + (x >> 3);   // XCD-contiguous quarter index
    const int bkt = j >> 2;
    const int q = j & 3;
    if (bkt >= NCB) return;                   // 4 idle blocks (j 1252..1255)
    const int tid = threadIdx.x;

    __shared__ uint32_t cur4[4];
    __shared__ float swp[4];                              // per-wave sum_w partials
    __shared__ __align__(16) uint2 st4[4][KSLOT];         // 12.3 KB
    __shared__ __align__(16) uint32_t rows[2][5][KSLOT];  // 15.4 KB
    __shared__ float part[2][256];                        // 2 KB

    if (tid < 4) cur4[tid] = 0u;
    __syncthreads();

    // single scan of the bucket region: keep records with kl>>2 == q
    int cnt = (int)min(coarse_cnt[bkt], (uint32_t)BCAP);
    const uint2* region = recs + (size_t)bkt * BCAP;
    for (int i = tid; i < cnt; i += 256) {
        uint2 r = region[i];
        int kl = (int)((r.x >> 16) & 15u);
        if ((kl >> 2) == q) {
            uint32_t p = atomicAdd(&cur4[kl & 3], 1u);
            if (p < KSLOT) st4[kl & 3][p] = r;
        }
    }
    __syncthreads();

    const int b = tid & 127;
    const int grp = tid >> 7;         // 0/1
    const uint32_t bsh = (uint32_t)(b & 31);
    const int widx = b >> 5;

    for (int rnd = 0; rnd < 2; ++rnd) {
        // stage: 128-thread group grp handles list kl = rnd*2+grp
        int kl = rnd * 2 + grp;
        int c = min((int)cur4[kl], KSLOT);
        int T8 = (c + 7) & ~7;
        float sw = 0.f;
        for (int t = c + b; t < T8; t += 128) rows[grp][4][t] = 0u;  // w=0 pad
        for (int t = b; t < c; t += 128) {
            uint2 r = st4[kl][t];
            uint4 mw = bits4[r.x & 0xFFFFu];
            rows[grp][0][t] = mw.x;
            rows[grp][1][t] = mw.y;
            rows[grp][2][t] = mw.z;
            rows[grp][3][t] = mw.w;
            rows[grp][4][t] = r.y;
            sw += __uint_as_float(r.y);
        }
#pragma unroll
        for (int off = 32; off; off >>= 1) sw += __shfl_down(sw, off);
        if ((tid & 63) == 0) swp[tid >> 6] = sw;   // waves 0,1 -> kl0; 2,3 -> kl1
        __syncthreads();

        // accumulate: 256 threads = 128 batches x 2 record-halves, per k
#pragma unroll
        for (int kk = 0; kk < 2; ++kk) {
            int T8k = (min((int)cur4[rnd * 2 + kk], KSLOT) + 7) & ~7;
            const uint32_t* mrow = rows[kk][widx];
            const uint32_t* wrow = rows[kk][4];
            float a0 = 0.f, a1 = 0.f, a2 = 0.f, a3 = 0.f;
            for (int i = grp * 4; i < T8k; i += 8) {
                uint4 mm = *(const uint4*)(mrow + i);   // broadcast ds_read_b128
                uint4 ww = *(const uint4*)(wrow + i);
                a0 += __uint_as_float(ww.x & selmask(mm.x, bsh));
                a1 += __uint_as_float(ww.y & selmask(mm.y, bsh));
                a2 += __uint_as_float(ww.z & selmask(mm.z, bsh));
                a3 += __uint_as_float(ww.w & selmask(mm.w, bsh));
            }
            part[kk][tid] = (a0 + a1) + (a2 + a3);
        }
        __syncthreads();
        if (tid < 128) {
            int k0 = bkt * 16 + q * 4 + rnd * 2;
            if (k0 + 1 < NH) {
                float acc0 = part[0][tid] + part[0][tid + 128];
                float acc1 = part[1][tid] + part[1][tid + 128];
                float e0 = 2.f * acc0 - (swp[0] + swp[1]) + linear[NV + k0];
                float e1 = 2.f * acc1 - (swp[2] + swp[3]) + linear[NV + k0 + 1];
                float2 o = make_float2(tanhf(-e0), tanhf(-e1));
                *(float2*)(out + (size_t)tid * NH + k0) = o;  // k0 even -> aligned
            }
        }
        __syncthreads();   // rows/part/swp reuse guard
    }
}

extern "C" void kernel_launch(void* const* d_in, const int* in_sizes, int n_in,
                              void* d_out, int out_size, void* d_ws, size_t ws_size,
                              hipStream_t stream) {
    const float* linear = (const float*)d_in[0];
    const float* quad   = (const float*)d_in[1];
    const int*   s      = (const int*)d_in[2];
    const int*   adj    = (const int*)d_in[3];
    const int*   seg    = (const int*)d_in[5];
    const int E = in_sizes[5];
    float* out = (float*)d_out;

    char* ws = (char*)d_ws;
    uint32_t* bits       = (uint32_t*)(ws);
    uint32_t* coarse_cnt = (uint32_t*)(ws + 800000);
    uint2*    recs       = (uint2*)   (ws + 801280);

    pack_zero_kernel<<<(NV * 4 + 255) / 256, 256, 0, stream>>>(s, bits, coarse_cnt);
    const int nchunk = (E + CHUNK - 1) / CHUNK;       // 245
    coarse_split_kernel<<<nchunk, 256, 0, stream>>>(
        (const int4*)seg, (const int4*)adj, (const float4*)quad, coarse_cnt, recs, E);
    quarter_field_kernel<<<1256, 256, 0, stream>>>(coarse_cnt, recs, (const uint4*)bits,
                                                   linear, out);
}